// Round 2
// baseline (993.865 us; speedup 1.0000x reference)
//
#include <hip/hip_runtime.h>
#include <hip/hip_bf16.h>

// Problem constants (reference: T=2048, B=64, D=256, H=256)
constexpr int T = 2048;
constexpr int B = 64;
constexpr int D = 256;
constexpr int H = 256;
constexpr int M = T * B;        // 131072 GEMM rows
constexpr int N2 = 2 * H;       // 512 output feature dim (u1 | u2)

// ---------------------------------------------------------------------------
// Projection GEMM: out[m][n] = xs[m,:] @ [Wx1 | Wx2][:, n], written directly
// into d_out's ys region ([T,B,2H] = [M,512]).
// 128x128 tile, BK=16, 256 threads, 8x8 micro-tile per thread.
// LDS row stride 132 floats (= 33*16B, keeps float4 alignment, breaks
// power-of-2 bank patterns on the staging writes).
// ---------------------------------------------------------------------------
constexpr int BK = 16;
constexpr int LDSW = 132;       // padded row width in floats

__global__ __launch_bounds__(256, 4) void proj_gemm(
        const float* __restrict__ xs,
        const float* __restrict__ Wx1,
        const float* __restrict__ Wx2,
        float* __restrict__ out) {
    __shared__ float As[BK][LDSW];   // k-major: As[k][m], m in 0..127
    __shared__ float Bs[BK][LDSW];   // Bs[k][n], n in 0..127

    const int bm = blockIdx.x;             // 0..1023
    const int bn = blockIdx.y;             // 0..3
    const float* W = (bn < 2) ? Wx1 : Wx2;
    const int ncol0 = (bn & 1) * 128;      // column offset within W
    const int m0 = bm * 128;

    const int tid = threadIdx.x;
    const int tx = tid & 15;               // 0..15 -> N (8 cols each)
    const int ty = tid >> 4;               // 0..15 -> M (8 rows each)

    // staging indices
    const int ar = tid >> 1;               // A row 0..127
    const int akc = (tid & 1) * 8;         // A k-offset 0 or 8
    const int b_i0 = tid;                  // B float4 index 0..255
    const int b_i1 = tid + 256;            // 256..511

    float acc[8][8] = {};

    for (int k0 = 0; k0 < D; k0 += BK) {
        // --- stage A tile (128 m x 16 k), transposed into As[k][m] ---
        {
            const float4 v0 = *(const float4*)&xs[(size_t)(m0 + ar) * D + k0 + akc];
            const float4 v1 = *(const float4*)&xs[(size_t)(m0 + ar) * D + k0 + akc + 4];
            As[akc + 0][ar] = v0.x;
            As[akc + 1][ar] = v0.y;
            As[akc + 2][ar] = v0.z;
            As[akc + 3][ar] = v0.w;
            As[akc + 4][ar] = v1.x;
            As[akc + 5][ar] = v1.y;
            As[akc + 6][ar] = v1.z;
            As[akc + 7][ar] = v1.w;
        }
        // --- stage B tile (16 k x 128 n): 512 float4s, 2 per thread ---
        {
            const int r0 = b_i0 >> 5, c0 = (b_i0 & 31) * 4;
            const int r1 = b_i1 >> 5, c1 = (b_i1 & 31) * 4;
            *(float4*)&Bs[r0][c0] = *(const float4*)&W[(size_t)(k0 + r0) * H + ncol0 + c0];
            *(float4*)&Bs[r1][c1] = *(const float4*)&W[(size_t)(k0 + r1) * H + ncol0 + c1];
        }
        __syncthreads();

        #pragma unroll
        for (int k = 0; k < BK; ++k) {
            const float4 a0 = *(const float4*)&As[k][ty * 8];
            const float4 a1 = *(const float4*)&As[k][ty * 8 + 4];
            const float4 b0 = *(const float4*)&Bs[k][tx * 8];
            const float4 b1 = *(const float4*)&Bs[k][tx * 8 + 4];
            const float av[8] = {a0.x, a0.y, a0.z, a0.w, a1.x, a1.y, a1.z, a1.w};
            const float bv[8] = {b0.x, b0.y, b0.z, b0.w, b1.x, b1.y, b1.z, b1.w};
            #pragma unroll
            for (int i = 0; i < 8; ++i)
                #pragma unroll
                for (int j = 0; j < 8; ++j)
                    acc[i][j] = fmaf(av[i], bv[j], acc[i][j]);
        }
        __syncthreads();
    }

    // --- store 8x8 micro-tile, two float4 per row ---
    const int ncol = bn * 128 + tx * 8;
    #pragma unroll
    for (int i = 0; i < 8; ++i) {
        const size_t row = (size_t)(m0 + ty * 8 + i);
        float4 v0, v1;
        v0.x = acc[i][0]; v0.y = acc[i][1]; v0.z = acc[i][2]; v0.w = acc[i][3];
        v1.x = acc[i][4]; v1.y = acc[i][5]; v1.z = acc[i][6]; v1.w = acc[i][7];
        *(float4*)&out[row * N2 + ncol] = v0;
        *(float4*)&out[row * N2 + ncol + 4] = v1;
    }
}

// ---------------------------------------------------------------------------
// Scan: each thread owns one (b,h) chain; in-place over d_out's ys region.
//   g1 = w1*p1 - w2*p2 + u1 ; g2 = w2*p1 + w1*p2 + u2 ; relu; write back.
// Finals f1,f2 appended after ys.
// ---------------------------------------------------------------------------
__global__ __launch_bounds__(64) void rot_scan(const float* __restrict__ h1,
                                               const float* __restrict__ h2,
                                               const float* __restrict__ w1,
                                               const float* __restrict__ w2,
                                               float* __restrict__ out) {
    const int g = blockIdx.x * 64 + threadIdx.x;   // 0..16383
    const int h = g & (H - 1);
    const int b = g >> 8;

    const float c1 = w1[h];
    const float c2 = w2[h];
    float p1 = h1[b * H + h];
    float p2 = h2[b * H + h];

    float* base = out + (size_t)b * N2 + h;        // ys[t][b][h], t-stride B*N2
    const size_t tstride = (size_t)B * N2;

    #pragma unroll 4
    for (int t = 0; t < T; ++t) {
        const float u1 = base[0];
        const float u2 = base[H];
        const float g1 = fmaf(c1, p1, fmaf(-c2, p2, u1));
        const float g2 = fmaf(c2, p1, fmaf(c1, p2, u2));
        p1 = fmaxf(g1, 0.0f);
        p2 = fmaxf(g2, 0.0f);
        base[0] = p1;
        base[H] = p2;
        base += tstride;
    }

    float* fin = out + (size_t)T * B * N2;
    fin[b * H + h] = p1;               // f1
    fin[B * H + b * H + h] = p2;       // f2
}

// ---------------------------------------------------------------------------
extern "C" void kernel_launch(void* const* d_in, const int* in_sizes, int n_in,
                              void* d_out, int out_size, void* d_ws, size_t ws_size,
                              hipStream_t stream) {
    const float* xs  = (const float*)d_in[0];
    const float* h1  = (const float*)d_in[1];
    const float* h2  = (const float*)d_in[2];
    const float* w1  = (const float*)d_in[3];
    const float* w2  = (const float*)d_in[4];
    const float* Wx1 = (const float*)d_in[5];
    const float* Wx2 = (const float*)d_in[6];
    float* out = (float*)d_out;

    // Stage 1: projections straight into the ys region of d_out.
    dim3 ggrid(M / 128, N2 / 128);
    proj_gemm<<<ggrid, 256, 0, stream>>>(xs, Wx1, Wx2, out);

    // Stage 2: in-place rotation/ReLU scan + final states.
    rot_scan<<<(B * H) / 64, 64, 0, stream>>>(h1, h2, w1, w2, out);
}

// Round 4
// 832.219 us; speedup vs baseline: 1.1942x; 1.1942x over previous
//
#include <hip/hip_runtime.h>
#include <hip/hip_bf16.h>

// Problem constants (reference: T=2048, B=64, D=256, H=256)
constexpr int T = 2048;
constexpr int B = 64;
constexpr int D = 256;
constexpr int H = 256;
constexpr int M = T * B;        // 131072 GEMM rows
constexpr int N2 = 2 * H;       // 512 output feature dim (u1 | u2)

// ---------------------------------------------------------------------------
// Projection GEMM: out[m][n] = xs[m,:] @ [Wx1 | Wx2][:, n], written directly
// into d_out's ys region ([T,B,2H] = [M,512]).
// 128x128 tile, BK=32, 256 threads.
// Micro-tile per thread: 2x2 quadrants of 4x4 (rows ty*4 / 64+ty*4,
// cols tx*4 / 64+tx*4): A-reads are 4-address broadcasts, B-reads are
// 256B-contiguous 2-way patterns — both conflict-free per m136.
// Accumulator expressed as float2 pairs so the backend can form
// v_pk_fma_f32 (if full-rate on gfx950, halves the VALU cost).
// ---------------------------------------------------------------------------
constexpr int BK = 32;
constexpr int LDSW = 132;       // padded row stride in floats (33*16B -> float4-aligned)

__global__ __launch_bounds__(256, 4) void proj_gemm(
        const float* __restrict__ xs,
        const float* __restrict__ Wx1,
        const float* __restrict__ Wx2,
        float* __restrict__ out) {
    __shared__ float As[BK][LDSW];   // k-major: As[k][m], m in 0..127
    __shared__ float Bs[BK][LDSW];   // Bs[k][n], n in 0..127

    const int bm = blockIdx.x;             // 0..1023
    const int bn = blockIdx.y;             // 0..3
    const float* W = (bn < 2) ? Wx1 : Wx2;
    const int ncol0w = (bn & 1) * 128;     // column offset within W
    const int m0 = bm * 128;

    const int tid = threadIdx.x;
    const int tx = tid & 15;               // 0..15 -> N quadrant base
    const int ty = tid >> 4;               // 0..15 -> M quadrant base

    // A staging: thread covers row ar, k-range akc..akc+15 (4 float4 loads)
    const int ar = tid >> 1;               // 0..127
    const int akc = (tid & 1) * 16;        // 0 or 16

    // acc[qi][qj][i][jp]: row quadrant, col quadrant, row 0..3, col-pair 0..1
    float2 acc[2][2][4][2];
    #pragma unroll
    for (int qi = 0; qi < 2; ++qi)
        #pragma unroll
        for (int qj = 0; qj < 2; ++qj)
            #pragma unroll
            for (int i = 0; i < 4; ++i)
                #pragma unroll
                for (int jp = 0; jp < 2; ++jp)
                    acc[qi][qj][i][jp] = make_float2(0.f, 0.f);

    for (int k0 = 0; k0 < D; k0 += BK) {
        // --- stage A tile (128 m x 32 k), transposed into As[k][m] ---
        {
            const float* src = &xs[(size_t)(m0 + ar) * D + k0 + akc];
            #pragma unroll
            for (int q = 0; q < 4; ++q) {
                const float4 v = *(const float4*)(src + q * 4);
                As[akc + q * 4 + 0][ar] = v.x;
                As[akc + q * 4 + 1][ar] = v.y;
                As[akc + q * 4 + 2][ar] = v.z;
                As[akc + q * 4 + 3][ar] = v.w;
            }
        }
        // --- stage B tile (32 k x 128 n): 1024 float4s, 4 per thread ---
        {
            #pragma unroll
            for (int q = 0; q < 4; ++q) {
                const int idx = tid + 256 * q;     // 0..1023
                const int r = idx >> 5;            // 0..31
                const int c = (idx & 31) * 4;      // 0..124
                *(float4*)&Bs[r][c] =
                    *(const float4*)&W[(size_t)(k0 + r) * H + ncol0w + c];
            }
        }
        __syncthreads();

        #pragma unroll
        for (int k = 0; k < BK; ++k) {
            const float4 a0 = *(const float4*)&As[k][ty * 4];
            const float4 a1 = *(const float4*)&As[k][64 + ty * 4];
            const float4 b0 = *(const float4*)&Bs[k][tx * 4];
            const float4 b1 = *(const float4*)&Bs[k][64 + tx * 4];
            const float av[2][4] = {{a0.x, a0.y, a0.z, a0.w},
                                    {a1.x, a1.y, a1.z, a1.w}};
            const float2 bv[2][2] = {{make_float2(b0.x, b0.y), make_float2(b0.z, b0.w)},
                                     {make_float2(b1.x, b1.y), make_float2(b1.z, b1.w)}};
            #pragma unroll
            for (int qi = 0; qi < 2; ++qi)
                #pragma unroll
                for (int i = 0; i < 4; ++i) {
                    const float a = av[qi][i];
                    #pragma unroll
                    for (int qj = 0; qj < 2; ++qj)
                        #pragma unroll
                        for (int jp = 0; jp < 2; ++jp) {
                            float2& c = acc[qi][qj][i][jp];
                            const float2 b = bv[qj][jp];
                            c.x = fmaf(a, b.x, c.x);   // pairs -> v_pk_fma_f32
                            c.y = fmaf(a, b.y, c.y);
                        }
                }
        }
        __syncthreads();
    }

    // --- store: 2x2 quadrants of 4x4, float4 per row-quadrant ---
    #pragma unroll
    for (int qi = 0; qi < 2; ++qi) {
        #pragma unroll
        for (int i = 0; i < 4; ++i) {
            const size_t row = (size_t)(m0 + qi * 64 + ty * 4 + i);
            #pragma unroll
            for (int qj = 0; qj < 2; ++qj) {
                const int col = bn * 128 + qj * 64 + tx * 4;
                float4 v;
                v.x = acc[qi][qj][i][0].x;
                v.y = acc[qi][qj][i][0].y;
                v.z = acc[qi][qj][i][1].x;
                v.w = acc[qi][qj][i][1].y;
                *(float4*)&out[row * N2 + col] = v;
            }
        }
    }
}

// ---------------------------------------------------------------------------
// Scan: each thread owns one (b,h) chain; in-place over d_out's ys region.
// P=16-deep register pipeline: load u[t+P] while computing u[t], so ~32
// loads (+stores) stay outstanding per lane — enough bytes in flight to
// approach HBM BW at 1 wave/CU. P=16 is the max: loads+stores share the
// vmcnt counter (gfx9), 4P ~= 62 <= 63.
// ---------------------------------------------------------------------------
constexpr int P = 16;

__global__ __launch_bounds__(64) void rot_scan(const float* __restrict__ h1,
                                               const float* __restrict__ h2,
                                               const float* __restrict__ w1,
                                               const float* __restrict__ w2,
                                               float* __restrict__ out) {
    const int g = blockIdx.x * 64 + threadIdx.x;   // 0..16383
    const int h = g & (H - 1);
    const int b = g >> 8;

    const float c1 = w1[h];
    const float c2 = w2[h];
    float p1 = h1[b * H + h];
    float p2 = h2[b * H + h];

    float* base = out + (size_t)b * N2 + h;        // ys[t][b][h], t-stride B*N2
    const size_t ts = (size_t)B * N2;

    float u1b[P], u2b[P];
    #pragma unroll
    for (int j = 0; j < P; ++j) {
        u1b[j] = base[(size_t)j * ts];
        u2b[j] = base[(size_t)j * ts + H];
    }

    for (int tt = 0; tt < T; tt += P) {
        #pragma unroll
        for (int j = 0; j < P; ++j) {
            const float u1 = u1b[j];
            const float u2 = u2b[j];
            const float g1 = fmaf(c1, p1, fmaf(-c2, p2, u1));
            const float g2 = fmaf(c2, p1, fmaf(c1, p2, u2));
            p1 = fmaxf(g1, 0.0f);
            p2 = fmaxf(g2, 0.0f);
            float* cur = base + (size_t)(tt + j) * ts;
            cur[0] = p1;
            cur[H] = p2;
            const int tn = tt + j + P;
            if (tn < T) {
                u1b[j] = base[(size_t)tn * ts];
                u2b[j] = base[(size_t)tn * ts + H];
            }
        }
    }

    float* fin = out + (size_t)T * B * N2;
    fin[b * H + h] = p1;               // f1
    fin[B * H + b * H + h] = p2;       // f2
}

// ---------------------------------------------------------------------------
extern "C" void kernel_launch(void* const* d_in, const int* in_sizes, int n_in,
                              void* d_out, int out_size, void* d_ws, size_t ws_size,
                              hipStream_t stream) {
    const float* xs  = (const float*)d_in[0];
    const float* h1  = (const float*)d_in[1];
    const float* h2  = (const float*)d_in[2];
    const float* w1  = (const float*)d_in[3];
    const float* w2  = (const float*)d_in[4];
    const float* Wx1 = (const float*)d_in[5];
    const float* Wx2 = (const float*)d_in[6];
    float* out = (float*)d_out;

    // Stage 1: projections straight into the ys region of d_out.
    dim3 ggrid(M / 128, N2 / 128);
    proj_gemm<<<ggrid, 256, 0, stream>>>(xs, Wx1, Wx2, out);

    // Stage 2: in-place rotation/ReLU scan + final states.
    rot_scan<<<(B * H) / 64, 64, 0, stream>>>(h1, h2, w1, w2, out);
}